// Round 5
// baseline (172.467 us; speedup 1.0000x reference)
//
#include <hip/hip_runtime.h>
#include <hip/hip_bf16.h>

#define S 16
#define C 8
#define SC 128
#define TT 500
#define NN 1500
#define NF4 375
#define CHUNK 32
#define NCHUNK 16

__device__ __forceinline__ float fexp2(float x) { return exp2f(x); }
__device__ __forceinline__ float flog2(float x) { return log2f(x); }

#define L2E 1.4426950408889634f
#define LN2 0.6931471805599453f

typedef float f4v __attribute__((ext_vector_type(4)));

// dst = Asrc * Bsrc per chain (8 x 16x16), 1024 threads, 2 entries each
#define MM(dst, Asrc, Bsrc) do {                                          \
    __syncthreads();                                                      \
    for (int e_ = tid; e_ < 2048; e_ += 1024) {                           \
        const int c_ = e_ >> 8;                                           \
        const int i_ = (e_ >> 4) & 15;                                    \
        const int l_ = e_ & 15;                                           \
        float acc_ = 0.f;                                                 \
        _Pragma("unroll")                                                 \
        for (int s_ = 0; s_ < S; ++s_)                                    \
            acc_ += Asrc[(c_ * S + i_) * S + s_] *                        \
                    Bsrc[(c_ * S + s_) * S + l_];                         \
        dst[(c_ * S + i_) * S + l_] = acc_;                              \
    }                                                                     \
} while (0)

// ---------------- Kernel 1: ALL small work incl. full scan -----------------
__global__ __launch_bounds__(1024) void setup_all(
    const float* __restrict__ usi,   // (16,8)
    const float* __restrict__ ucw,   // (500,8)
    const float* __restrict__ uem,   // (16,1500)
    const float* __restrict__ utm,   // (8,16,16)
    float* __restrict__ ws_lcw,      // (500,8)  log chain weights
    float* __restrict__ ws_Ws,       // (500,16) W[t][s] = LSE_c(h+lcw)
    float* __restrict__ ws_emlse,    // (16)
    float* __restrict__ out3)        // (500,16,8) natural-log h
{
    __shared__ float bufT[C * S * S];
    __shared__ float bufX[C * S * S];
    __shared__ float bufY[C * S * S];
    __shared__ float bufZ[C * S * S];
    __shared__ float qall[NCHUNK * SC];   // chunk-start probs [k][c*16+s]
    __shared__ float qbuf[SC];
    __shared__ float lcwS[TT * C];        // log chain weights
    __shared__ float cwpS[TT * C];        // prob chain weights
    const int tid = threadIdx.x;

    // (a) log_softmax chain weights over C per row t
    for (int t = tid; t < TT; t += 1024) {
        float x[C]; float m = -1e30f;
#pragma unroll
        for (int cc = 0; cc < C; ++cc) { x[cc] = ucw[t * C + cc]; m = fmaxf(m, x[cc]); }
        float acc = 0.f;
#pragma unroll
        for (int cc = 0; cc < C; ++cc) acc += fexp2((x[cc] - m) * L2E);
        const float lse = m + flog2(acc) * LN2;
#pragma unroll
        for (int cc = 0; cc < C; ++cc) {
            const float v = x[cc] - lse;
            lcwS[t * C + cc] = v;
            ws_lcw[t * C + cc] = v;
            cwpS[t * C + cc] = fexp2(v * L2E);
        }
    }

    // (b) emission LSE per state (max-free; uem ~ N(0,1))
    if (tid < 256) {
        const int row = tid >> 4;
        const int ln  = tid & 15;
        const float* rp = uem + row * NN;
        float a = 0.f;
        for (int n = ln; n < NN; n += 16) a += fexp2(rp[n] * L2E);
#pragma unroll
        for (int off = 8; off >= 1; off >>= 1) a += __shfl_xor(a, off);
        if (ln == 0) ws_emlse[row] = flog2(a) * LN2;
    }

    // (c) softmax transition rows (over s'), PROB domain -> bufT
    if (tid < SC) {
        float x[S]; float m = -1e30f;
#pragma unroll
        for (int k = 0; k < S; ++k) { x[k] = utm[tid * S + k]; m = fmaxf(m, x[k]); }
        float acc = 0.f; float e[S];
#pragma unroll
        for (int k = 0; k < S; ++k) { e[k] = fexp2((x[k] - m) * L2E); acc += e[k]; }
        const float inv = 1.f / acc;
#pragma unroll
        for (int k = 0; k < S; ++k) bufT[tid * S + k] = e[k] * inv;
    }

    // (d) p0 = softmax over states per chain -> qbuf, qall[0]
    if (tid < C) {
        const int cc = tid;
        float x[S]; float m = -1e30f;
#pragma unroll
        for (int s0 = 0; s0 < S; ++s0) { x[s0] = usi[s0 * C + cc]; m = fmaxf(m, x[s0]); }
        float acc = 0.f; float e[S];
#pragma unroll
        for (int s0 = 0; s0 < S; ++s0) { e[s0] = fexp2((x[s0] - m) * L2E); acc += e[s0]; }
        const float inv = 1.f / acc;
#pragma unroll
        for (int s0 = 0; s0 < S; ++s0) {
            const float v = e[s0] * inv;
            qbuf[cc * S + s0] = v;
            qall[cc * S + s0] = v;
        }
    }

    // (e) A = T^32 per chain
    MM(bufX, bufT, bufT);   // T^2
    MM(bufY, bufX, bufX);   // T^4
    MM(bufZ, bufY, bufY);   // T^8
    MM(bufX, bufZ, bufZ);   // T^16
    MM(bufY, bufX, bufX);   // T^32 -> bufY
    __syncthreads();

    // (f) chunk starts: q_k = q_{k-1} * A
    const int c5 = tid >> 4;
    const int l5 = tid & 15;
    float Acol[S];
    if (tid < SC) {
#pragma unroll
        for (int s0 = 0; s0 < S; ++s0) Acol[s0] = bufY[(c5 * S + s0) * S + l5];
    }
    for (int k = 1; k < NCHUNK; ++k) {
        float acc = 0.f;
        if (tid < SC) {
#pragma unroll
            for (int s0 = 0; s0 < S; ++s0) acc += qbuf[c5 * S + s0] * Acol[s0];
        }
        __syncthreads();
        if (tid < SC) {
            qbuf[c5 * S + l5] = acc;
            qall[k * SC + c5 * S + l5] = acc;
        }
        __syncthreads();
    }

    // (g) 16 waves x 32 recursion steps, register/shfl only
    const int w = tid >> 6;
    const int lane = tid & 63;
    const int c = lane >> 3;
    const int j = lane & 7;
    float Ta[S], Tb[S];
#pragma unroll
    for (int s0 = 0; s0 < S; ++s0) {
        Ta[s0] = bufT[(c * S + s0) * S + j];
        Tb[s0] = bufT[(c * S + s0) * S + j + 8];
    }
    float pa = qall[w * SC + c * S + j];
    float pb = qall[w * SC + c * S + j + 8];
    const int base = c << 3;

    for (int i = 0; i < CHUNK; ++i) {
        const int t = w * CHUNK + i;
        if (t >= TT) break;
        const float la = flog2(pa) * LN2;
        const float lb = flog2(pb) * LN2;
        out3[(size_t)t * SC + j * C + c]       = la;
        out3[(size_t)t * SC + (j + 8) * C + c] = lb;
        // W[t][s] = ln sum_c p[s,c]*cw[t,c]
        const float cw = cwpS[t * C + c];
        float ea = pa * cw, eb = pb * cw;
        ea += __shfl_xor(ea, 8); ea += __shfl_xor(ea, 16); ea += __shfl_xor(ea, 32);
        eb += __shfl_xor(eb, 8); eb += __shfl_xor(eb, 16); eb += __shfl_xor(eb, 32);
        if (c == 0) {
            ws_Ws[t * S + j]     = flog2(ea) * LN2;
            ws_Ws[t * S + j + 8] = flog2(eb) * LN2;
        }
        // step
        float pv[S];
#pragma unroll
        for (int q = 0; q < 8; ++q) {
            pv[q]     = __shfl(pa, base + q);
            pv[q + 8] = __shfl(pb, base + q);
        }
        float a0 = 0.f, a1 = 0.f, a2 = 0.f, a3 = 0.f;
        float b0 = 0.f, b1 = 0.f, b2 = 0.f, b3 = 0.f;
#pragma unroll
        for (int s0 = 0; s0 < S; s0 += 4) {
            a0 = fmaf(pv[s0],     Ta[s0],     a0);
            a1 = fmaf(pv[s0 + 1], Ta[s0 + 1], a1);
            a2 = fmaf(pv[s0 + 2], Ta[s0 + 2], a2);
            a3 = fmaf(pv[s0 + 3], Ta[s0 + 3], a3);
            b0 = fmaf(pv[s0],     Tb[s0],     b0);
            b1 = fmaf(pv[s0 + 1], Tb[s0 + 1], b1);
            b2 = fmaf(pv[s0 + 2], Tb[s0 + 2], b2);
            b3 = fmaf(pv[s0 + 3], Tb[s0 + 3], b3);
        }
        pa = (a0 + a1) + (a2 + a3);
        pb = (b0 + b1) + (b2 + b3);
    }
}

// ---------------- Kernel 2: out1 (tiny, 3 MB) ------------------------------
__global__ __launch_bounds__(256) void out1_kernel(
    const float* __restrict__ uem,     // (16,1500)
    const float* __restrict__ ws_Ws,   // (500,16)
    const float* __restrict__ ws_emlse,// (16)
    float* __restrict__ out1)          // (500,1500)
{
    const int t = blockIdx.x;
    const int tid = threadIdx.x;
    __shared__ float g[S];
    if (tid < S) g[tid] = fexp2((ws_Ws[t * S + tid] - ws_emlse[tid]) * L2E);
    __syncthreads();

    for (int idx = tid; idx < NF4; idx += 256) {
        f4v acc = {0.f, 0.f, 0.f, 0.f};
#pragma unroll
        for (int s0 = 0; s0 < S; ++s0) {
            const f4v e = *(const f4v*)(uem + s0 * NN + idx * 4);
            const float gs = g[s0];
            acc.x += fexp2(e.x * L2E) * gs;
            acc.y += fexp2(e.y * L2E) * gs;
            acc.z += fexp2(e.z * L2E) * gs;
            acc.w += fexp2(e.w * L2E) * gs;
        }
        f4v r;
        r.x = flog2(acc.x) * LN2;
        r.y = flog2(acc.y) * LN2;
        r.z = flog2(acc.z) * LN2;
        r.w = flog2(acc.w) * LN2;
        *(f4v*)(out1 + (size_t)t * NN + idx * 4) = r;
    }
}

// ---------------- Kernel 3: big stream (384 MB), block = (s0, t) -----------
__global__ __launch_bounds__(256) void stream_kernel(
    const float* __restrict__ uem,     // (16,1500)
    const float* __restrict__ out3,    // (500,16,8)
    const float* __restrict__ ws_lcw,  // (500,8)
    const float* __restrict__ ws_emlse,// (16)
    float* __restrict__ out2)          // (500,16,8,1500)
{
    const int s0 = blockIdx.x;
    const int t  = blockIdx.y;
    const int tid = threadIdx.x;
    __shared__ float hcv[C];
    __shared__ float emv;
    if (tid < C) hcv[tid] = out3[(size_t)t * SC + s0 * C + tid] + ws_lcw[t * C + tid];
    if (tid == C) emv = ws_emlse[s0];
    __syncthreads();
    const float el = emv;

    float* o2 = out2 + (size_t)t * SC * NN + (size_t)s0 * C * NN;
    for (int idx = tid; idx < NF4; idx += 256) {
        f4v e = *(const f4v*)(uem + s0 * NN + idx * 4);
        e -= el;
        float* o = o2 + idx * 4;
#pragma unroll
        for (int cc = 0; cc < C; ++cc) {
            *(f4v*)(o + (size_t)cc * NN) = e + hcv[cc];
        }
    }
}

extern "C" void kernel_launch(void* const* d_in, const int* in_sizes, int n_in,
                              void* d_out, int out_size, void* d_ws, size_t ws_size,
                              hipStream_t stream)
{
    const float* usi = (const float*)d_in[0];   // (16,8)
    const float* ucw = (const float*)d_in[1];   // (500,8)
    const float* uem = (const float*)d_in[2];   // (16,1,1500)
    const float* utm = (const float*)d_in[3];   // (8,16,16)

    float* out  = (float*)d_out;
    float* out1 = out;                                   // 750000
    float* out2 = out + 750000;                          // 96000000
    float* out3 = out + 750000 + 96000000;               // 64000

    float* ws       = (float*)d_ws;
    float* ws_lcw   = ws;             // 4000
    float* ws_Ws    = ws + 4000;      // 8000
    float* ws_emlse = ws + 12000;     // 16

    setup_all<<<1, 1024, 0, stream>>>(usi, ucw, uem, utm,
                                      ws_lcw, ws_Ws, ws_emlse, out3);
    out1_kernel<<<TT, 256, 0, stream>>>(uem, ws_Ws, ws_emlse, out1);
    stream_kernel<<<dim3(S, TT), 256, 0, stream>>>(uem, out3, ws_lcw, ws_emlse, out2);
}

// Round 6
// 132.205 us; speedup vs baseline: 1.3045x; 1.3045x over previous
//
#include <hip/hip_runtime.h>
#include <hip/hip_bf16.h>

#define S 16
#define C 8
#define SC 128
#define TT 500
#define NN 1500
#define NF4 375
#define CHUNK 25
#define NCHUNK 20

__device__ __forceinline__ float fexp2(float x) { return exp2f(x); }
__device__ __forceinline__ float flog2(float x) { return log2f(x); }

#define L2E 1.4426950408889634f
#define LN2 0.6931471805599453f

typedef float f4v __attribute__((ext_vector_type(4)));

// ---------------- Kernel 1: setup (1 block, 256 threads) -------------------
#define MM(dst, Asrc, Bsrc) do {                                          \
    __syncthreads();                                                      \
    {   const int c_ = tid >> 5; const int e0_ = tid & 31;                \
        for (int r_ = 0; r_ < 8; ++r_) {                                  \
            const int e_ = e0_ + (r_ << 5);                               \
            const int i_ = e_ >> 4; const int l_ = e_ & 15;               \
            float acc_ = 0.f;                                             \
            _Pragma("unroll")                                             \
            for (int s_ = 0; s_ < S; ++s_)                                \
                acc_ += Asrc[(c_ * S + i_) * S + s_] *                    \
                        Bsrc[(c_ * S + s_) * S + l_];                     \
            dst[(c_ * S + i_) * S + l_] = acc_;                          \
        } }                                                               \
} while (0)

__global__ __launch_bounds__(256) void hmm_setup(
    const float* __restrict__ usi,   // (16,8)
    const float* __restrict__ ucw,   // (500,8)
    const float* __restrict__ uem,   // (16,1500)
    const float* __restrict__ utm,   // (8,16,16)
    float* __restrict__ ws_lcw,      // (500,8)  log chain weights
    float* __restrict__ ws_cwp,      // (500,8)  prob chain weights
    float* __restrict__ ws_pT,       // (8,16,16) prob-domain T
    float* __restrict__ ws_q,        // (20,8,16) chunk-start probs
    float* __restrict__ ws_emlse)    // (16)
{
    __shared__ float bufT[C * S * S];
    __shared__ float bufX[C * S * S];
    __shared__ float bufY[C * S * S];
    __shared__ float bufZ[C * S * S];
    __shared__ float qbuf[C * S];
    const int tid = threadIdx.x;

    // log_softmax chain weights over C per row t (+ prob domain)
    for (int t = tid; t < TT; t += 256) {
        float x[C]; float m = -1e30f;
#pragma unroll
        for (int cc = 0; cc < C; ++cc) { x[cc] = ucw[t * C + cc]; m = fmaxf(m, x[cc]); }
        float acc = 0.f;
#pragma unroll
        for (int cc = 0; cc < C; ++cc) acc += fexp2((x[cc] - m) * L2E);
        const float lse = m + flog2(acc) * LN2;
#pragma unroll
        for (int cc = 0; cc < C; ++cc) {
            const float v = x[cc] - lse;
            ws_lcw[t * C + cc] = v;
            ws_cwp[t * C + cc] = fexp2(v * L2E);
        }
    }

    // emission LSE per state (max-free; uem ~ N(0,1))
    {
        const int row = tid >> 4;
        const int ln  = tid & 15;
        const float* rp = uem + row * NN;
        float a = 0.f;
        for (int n = ln; n < NN; n += 16) a += fexp2(rp[n] * L2E);
#pragma unroll
        for (int off = 8; off >= 1; off >>= 1) a += __shfl_xor(a, off);
        if (ln == 0) ws_emlse[row] = flog2(a) * LN2;
    }

    // softmax transition rows (over s'), PROB domain
    if (tid < SC) {
        float x[S]; float m = -1e30f;
#pragma unroll
        for (int k = 0; k < S; ++k) { x[k] = utm[tid * S + k]; m = fmaxf(m, x[k]); }
        float acc = 0.f; float e[S];
#pragma unroll
        for (int k = 0; k < S; ++k) { e[k] = fexp2((x[k] - m) * L2E); acc += e[k]; }
        const float inv = 1.f / acc;
#pragma unroll
        for (int k = 0; k < S; ++k) {
            const float v = e[k] * inv;
            bufT[tid * S + k] = v;
            ws_pT[tid * S + k] = v;
        }
    }

    // p0 = softmax over states per chain
    if (tid < C) {
        const int cc = tid;
        float x[S]; float m = -1e30f;
#pragma unroll
        for (int s0 = 0; s0 < S; ++s0) { x[s0] = usi[s0 * C + cc]; m = fmaxf(m, x[s0]); }
        float acc = 0.f; float e[S];
#pragma unroll
        for (int s0 = 0; s0 < S; ++s0) { e[s0] = fexp2((x[s0] - m) * L2E); acc += e[s0]; }
        const float inv = 1.f / acc;
#pragma unroll
        for (int s0 = 0; s0 < S; ++s0) {
            const float v = e[s0] * inv;
            qbuf[cc * S + s0] = v;
            ws_q[cc * S + s0] = v;
        }
    }

    // A = T^25 per chain
    MM(bufX, bufT, bufT);   // T^2
    MM(bufY, bufX, bufX);   // T^4
    MM(bufZ, bufY, bufY);   // T^8
    MM(bufX, bufZ, bufZ);   // T^16
    MM(bufY, bufX, bufZ);   // T^24
    MM(bufX, bufY, bufT);   // T^25
    __syncthreads();

    // chunk starts: q_k = q_{k-1} * A
    const int c5 = tid >> 4;
    const int l5 = tid & 15;
    float Acol[S];
    if (tid < 128) {
#pragma unroll
        for (int s0 = 0; s0 < S; ++s0) Acol[s0] = bufX[(c5 * S + s0) * S + l5];
    }
    for (int k = 1; k < NCHUNK; ++k) {
        float acc = 0.f;
        if (tid < 128) {
#pragma unroll
            for (int s0 = 0; s0 < S; ++s0) acc += qbuf[c5 * S + s0] * Acol[s0];
        }
        __syncthreads();
        if (tid < 128) {
            qbuf[c5 * S + l5] = acc;
            ws_q[k * SC + c5 * S + l5] = acc;
        }
        __syncthreads();
    }
}

// ---------------- Kernel 2: 20 parallel chunks of 25 serial steps ----------
// Emits out3 (log h) and gval[t][s] = (sum_c p*cw)/exp(emlse[s]).
__global__ __launch_bounds__(64) void hmm_chunks(
    const float* __restrict__ ws_pT, // (8,16,16)
    const float* __restrict__ ws_q,  // (20,8,16)
    const float* __restrict__ ws_cwp,// (500,8)
    const float* __restrict__ ws_emlse, // (16)
    float* __restrict__ out3,        // (500,16,8)
    float* __restrict__ ws_gval)     // (500,16)
{
    const int k = blockIdx.x;
    const int lane = threadIdx.x;
    const int c = lane >> 3;
    const int j = lane & 7;

    float Ta[S], Tb[S];
#pragma unroll
    for (int s0 = 0; s0 < S; ++s0) {
        Ta[s0] = ws_pT[(c * S + s0) * S + j];
        Tb[s0] = ws_pT[(c * S + s0) * S + j + 8];
    }
    float pa = ws_q[k * SC + c * S + j];
    float pb = ws_q[k * SC + c * S + j + 8];
    const float invEa = fexp2(-ws_emlse[j] * L2E);
    const float invEb = fexp2(-ws_emlse[j + 8] * L2E);

    const int base = c << 3;
    for (int i = 0; i < CHUNK; ++i) {
        const int t = k * CHUNK + i;
        const float la = flog2(pa) * LN2;
        const float lb = flog2(pb) * LN2;
        out3[(size_t)t * SC + j * C + c]       = la;
        out3[(size_t)t * SC + (j + 8) * C + c] = lb;

        const float cw = ws_cwp[t * C + c];
        float ea = pa * cw, eb = pb * cw;
        ea += __shfl_xor(ea, 8); ea += __shfl_xor(ea, 16); ea += __shfl_xor(ea, 32);
        eb += __shfl_xor(eb, 8); eb += __shfl_xor(eb, 16); eb += __shfl_xor(eb, 32);
        if (lane < 8) {
            ws_gval[t * S + lane]     = ea * invEa;
            ws_gval[t * S + lane + 8] = eb * invEb;
        }
        if (i == CHUNK - 1) break;

        float pv[S];
#pragma unroll
        for (int q = 0; q < 8; ++q) {
            pv[q]     = __shfl(pa, base + q);
            pv[q + 8] = __shfl(pb, base + q);
        }
        float a0 = 0.f, a1 = 0.f, a2 = 0.f, a3 = 0.f;
        float b0 = 0.f, b1 = 0.f, b2 = 0.f, b3 = 0.f;
#pragma unroll
        for (int s0 = 0; s0 < S; s0 += 4) {
            a0 = fmaf(pv[s0],     Ta[s0],     a0);
            a1 = fmaf(pv[s0 + 1], Ta[s0 + 1], a1);
            a2 = fmaf(pv[s0 + 2], Ta[s0 + 2], a2);
            a3 = fmaf(pv[s0 + 3], Ta[s0 + 3], a3);
            b0 = fmaf(pv[s0],     Tb[s0],     b0);
            b1 = fmaf(pv[s0 + 1], Tb[s0 + 1], b1);
            b2 = fmaf(pv[s0 + 2], Tb[s0 + 2], b2);
            b3 = fmaf(pv[s0 + 3], Tb[s0 + 3], b3);
        }
        pa = (a0 + a1) + (a2 + a3);
        pb = (b0 + b1) + (b2 + b3);
    }
}

// ---------------- Kernel 3: fill-like linear stream of out2 ----------------
// Row view: out2 = 64000 rows x 1500 floats; row = t*128 + s*8 + c.
// Block b owns rows [32b, 32b+32) = 192 KB contiguous; written as 16
// row-pairs (pairs never straddle s or t since 8 | row boundaries).
__global__ __launch_bounds__(256) void stream_kernel(
    const float* __restrict__ uem,     // (16,1500)
    const float* __restrict__ out3,    // (500,16,8)
    const float* __restrict__ ws_lcw,  // (500,8)
    const float* __restrict__ ws_emlse,// (16)
    float* __restrict__ out2)          // (500,16,8,1500)
{
    const int tid = threadIdx.x;
    const int row0 = blockIdx.x << 5;
    float* outp = out2 + (size_t)row0 * NN;

    for (int rr = 0; rr < 16; ++rr) {
        const int r0 = row0 + rr * 2;
        const int t  = r0 >> 7;
        const int s  = (r0 >> 3) & 15;
        const int c0 = r0 & 7;
        const float el = ws_emlse[s];
        const float av0 = out3[r0]     + ws_lcw[t * C + c0]     - el;
        const float av1 = out3[r0 + 1] + ws_lcw[t * C + c0 + 1] - el;
        const float* rowp = uem + s * NN;
        float* po = outp + (size_t)rr * 2 * NN;
#pragma unroll
        for (int off = tid; off < 750; off += 256) {
            const bool hi = off >= NF4;
            const float a = hi ? av1 : av0;
            const int o = hi ? off - NF4 : off;
            f4v e = *(const f4v*)(rowp + o * 4);
            e += a;
            *(f4v*)(po + (size_t)off * 4) = e;
        }
    }
}

// ---------------- Kernel 4: out1 (3 MB) ------------------------------------
__global__ __launch_bounds__(256) void out1_kernel(
    const float* __restrict__ uem,     // (16,1500)
    const float* __restrict__ ws_gval, // (500,16)
    float* __restrict__ out1)          // (500,1500)
{
    const int t = blockIdx.x;
    const int tid = threadIdx.x;
    __shared__ float g[S];
    if (tid < S) g[tid] = ws_gval[t * S + tid];
    __syncthreads();

    for (int idx = tid; idx < NF4; idx += 256) {
        f4v acc = {0.f, 0.f, 0.f, 0.f};
#pragma unroll
        for (int s0 = 0; s0 < S; ++s0) {
            const f4v e = *(const f4v*)(uem + s0 * NN + idx * 4);
            const float gs = g[s0];
            acc.x += fexp2(e.x * L2E) * gs;
            acc.y += fexp2(e.y * L2E) * gs;
            acc.z += fexp2(e.z * L2E) * gs;
            acc.w += fexp2(e.w * L2E) * gs;
        }
        f4v r;
        r.x = flog2(acc.x) * LN2;
        r.y = flog2(acc.y) * LN2;
        r.z = flog2(acc.z) * LN2;
        r.w = flog2(acc.w) * LN2;
        *(f4v*)(out1 + (size_t)t * NN + idx * 4) = r;
    }
}

extern "C" void kernel_launch(void* const* d_in, const int* in_sizes, int n_in,
                              void* d_out, int out_size, void* d_ws, size_t ws_size,
                              hipStream_t stream)
{
    const float* usi = (const float*)d_in[0];   // (16,8)
    const float* ucw = (const float*)d_in[1];   // (500,8)
    const float* uem = (const float*)d_in[2];   // (16,1,1500)
    const float* utm = (const float*)d_in[3];   // (8,16,16)

    float* out  = (float*)d_out;
    float* out1 = out;                                   // 750000
    float* out2 = out + 750000;                          // 96000000
    float* out3 = out + 750000 + 96000000;               // 64000

    float* ws       = (float*)d_ws;
    float* ws_lcw   = ws;             // 4000
    float* ws_cwp   = ws + 4000;      // 4000
    float* ws_pT    = ws + 8000;      // 2048
    float* ws_q     = ws + 10048;     // 2560
    float* ws_emlse = ws + 12608;     // 16
    float* ws_gval  = ws + 12624;     // 8000

    hmm_setup<<<1, 256, 0, stream>>>(usi, ucw, uem, utm,
                                     ws_lcw, ws_cwp, ws_pT, ws_q, ws_emlse);
    hmm_chunks<<<NCHUNK, 64, 0, stream>>>(ws_pT, ws_q, ws_cwp, ws_emlse,
                                          out3, ws_gval);
    stream_kernel<<<2000, 256, 0, stream>>>(uem, out3, ws_lcw, ws_emlse, out2);
    out1_kernel<<<TT, 256, 0, stream>>>(uem, ws_gval, out1);
}